// Round 1
// baseline (732.814 us; speedup 1.0000x reference)
//
#include <hip/hip_runtime.h>
#include <math.h>

#define DD 64

// ---------------------------------------------------------------------------
// Kernel 1: hidden_e = (x @ W^T) * artanh(||x||)/||x||   (exact telescoped
// form of logmap0(mobius_matvec(W, x, c=1))).
// One wave per row; W staged in LDS row-major with +4 pad; per-lane k-rotation
// to avoid the 8-way bank conflict of stride-68 float4 reads.
// ---------------------------------------------------------------------------
__global__ __launch_bounds__(256) void hgcn_linear(const float* __restrict__ x,
                                                   const float* __restrict__ W,
                                                   float* __restrict__ he,
                                                   int n) {
  __shared__ float Wl[64][68];   // Wl[o][k] = W[o*64+k], row stride 272B (16B-aligned)
  __shared__ float xs[4][64];
  const int tid = threadIdx.x;
  for (int i = tid; i < 64 * 64; i += 256) {
    Wl[i >> 6][i & 63] = W[i];
  }
  const int wave = tid >> 6, lane = tid & 63;
  const int row = blockIdx.x * 4 + wave;
  float xv = 0.f;
  if (row < n) xv = x[row * DD + lane];
  xs[wave][lane] = xv;
  __syncthreads();
  if (row >= n) return;

  // wave-reduce ||x_row||^2
  float nx2 = xv * xv;
  #pragma unroll
  for (int m = 1; m < 64; m <<= 1) nx2 += __shfl_xor(nx2, m);
  float nx = fmaxf(sqrtf(nx2), 1e-15f);
  float z  = fminf(nx, 1.f - 1e-7f);
  float s  = atanhf(z) / nx;

  // lane `lane` computes mx[row][lane] = sum_k x[row][k] * W[lane][k]
  const int j0 = (lane >> 3) & 7;   // rotate k-start so same-start-bank lanes diverge
  float acc = 0.f;
  #pragma unroll
  for (int jj = 0; jj < 16; ++jj) {
    const int k = ((jj + j0) & 15) << 2;
    const float4 xk = *reinterpret_cast<const float4*>(&xs[wave][k]);
    const float4 wk = *reinterpret_cast<const float4*>(&Wl[lane][k]);
    acc = fmaf(xk.x, wk.x, acc);
    acc = fmaf(xk.y, wk.y, acc);
    acc = fmaf(xk.z, wk.z, acc);
    acc = fmaf(xk.w, wk.w, acc);
  }
  he[row * DD + lane] = acc * s;
}

// ---------------------------------------------------------------------------
// Kernel 2: support[row] += w * hidden_e[col]   (COO scatter-add)
// 16 lanes per edge, float4 per lane -> 256B coalesced gather per edge,
// 4 hardware fp32 atomics per lane.
// ---------------------------------------------------------------------------
__global__ __launch_bounds__(256) void hgcn_scatter(const float* __restrict__ he,
                                                    const int* __restrict__ ei,
                                                    const float* __restrict__ ew,
                                                    float* __restrict__ sup,
                                                    int ne) {
  const int t = blockIdx.x * 256 + threadIdx.x;
  const int e = t >> 4, l = t & 15;
  if (e >= ne) return;
  const int row = ei[e];
  const int col = ei[ne + e];
  const float w = ew[e];
  const float4 v = *reinterpret_cast<const float4*>(he + (size_t)col * DD + l * 4);
  float* dst = sup + (size_t)row * DD + l * 4;
  unsafeAtomicAdd(dst + 0, w * v.x);
  unsafeAtomicAdd(dst + 1, w * v.y);
  unsafeAtomicAdd(dst + 2, w * v.z);
  unsafeAtomicAdd(dst + 3, w * v.w);
}

// ---------------------------------------------------------------------------
// Kernel 3: out = proj(expmap0(relu(support)))
// relu(logmap0(expmap0(s))) == relu(s) exactly, so only one tanh per row.
// 16 lanes per row, float4 per lane; 16-lane shfl_xor reduction for the norm.
// ---------------------------------------------------------------------------
__global__ __launch_bounds__(256) void hgcn_final(const float* __restrict__ sup,
                                                  float* __restrict__ out,
                                                  int n) {
  const int t = blockIdx.x * 256 + threadIdx.x;
  const int r = t >> 4, l = t & 15;
  if (r >= n) return;
  float4 v = *reinterpret_cast<const float4*>(sup + (size_t)r * DD + l * 4);
  v.x = fmaxf(v.x, 0.f);
  v.y = fmaxf(v.y, 0.f);
  v.z = fmaxf(v.z, 0.f);
  v.w = fmaxf(v.w, 0.f);
  float p = v.x * v.x + v.y * v.y + v.z * v.z + v.w * v.w;
  p += __shfl_xor(p, 1);
  p += __shfl_xor(p, 2);
  p += __shfl_xor(p, 4);
  p += __shfl_xor(p, 8);
  const float nu = fmaxf(sqrtf(p), 1e-15f);
  const float th = tanhf(nu);
  float scale = th / nu;                     // expmap0 factor
  const float maxn = 1.0f - 4e-3f;
  if (th > maxn) scale = maxn / nu;          // proj clamp (||expmap0|| = tanh(nu))
  float4 o;
  o.x = v.x * scale;
  o.y = v.y * scale;
  o.z = v.z * scale;
  o.w = v.w * scale;
  *reinterpret_cast<float4*>(out + (size_t)r * DD + l * 4) = o;
}

extern "C" void kernel_launch(void* const* d_in, const int* in_sizes, int n_in,
                              void* d_out, int out_size, void* d_ws, size_t ws_size,
                              hipStream_t stream) {
  const float* x  = (const float*)d_in[0];
  const float* W  = (const float*)d_in[1];
  const float* ew = (const float*)d_in[2];
  const int*   ei = (const int*)d_in[3];
  const int n  = in_sizes[0] / DD;   // 50000
  const int ne = in_sizes[2];        // 800000

  float* he  = (float*)d_out;  // stage hidden_e in d_out (overwritten by epilogue)
  float* sup = (float*)d_ws;   // support accumulator, needs zeroing every call
  float* out = (float*)d_out;

  hipMemsetAsync(sup, 0, (size_t)n * DD * sizeof(float), stream);
  hipLaunchKernelGGL(hgcn_linear,  dim3((n + 3) / 4),            dim3(256), 0, stream, x, W, he, n);
  hipLaunchKernelGGL(hgcn_scatter, dim3((ne * 16 + 255) / 256),  dim3(256), 0, stream, he, ei, ew, sup, ne);
  hipLaunchKernelGGL(hgcn_final,   dim3((n * 16 + 255) / 256),   dim3(256), 0, stream, sup, out, n);
}

// Round 2
// 187.939 us; speedup vs baseline: 3.8992x; 3.8992x over previous
//
#include <hip/hip_runtime.h>
#include <math.h>

#define DD 64

// ---------------------------------------------------------------------------
// Kernel 1: hidden_e = (x @ W^T) * artanh(||x||)/||x||   (exact telescoped
// form of logmap0(mobius_matvec(W, x, c=1))).
// ---------------------------------------------------------------------------
__global__ __launch_bounds__(256) void hgcn_linear(const float* __restrict__ x,
                                                   const float* __restrict__ W,
                                                   float* __restrict__ he,
                                                   int n) {
  __shared__ float Wl[64][68];
  __shared__ float xs[4][64];
  const int tid = threadIdx.x;
  for (int i = tid; i < 64 * 64; i += 256) {
    Wl[i >> 6][i & 63] = W[i];
  }
  const int wave = tid >> 6, lane = tid & 63;
  const int row = blockIdx.x * 4 + wave;
  float xv = 0.f;
  if (row < n) xv = x[row * DD + lane];
  xs[wave][lane] = xv;
  __syncthreads();
  if (row >= n) return;

  float nx2 = xv * xv;
  #pragma unroll
  for (int m = 1; m < 64; m <<= 1) nx2 += __shfl_xor(nx2, m);
  float nx = fmaxf(sqrtf(nx2), 1e-15f);
  float z  = fminf(nx, 1.f - 1e-7f);
  float s  = atanhf(z) / nx;

  const int j0 = (lane >> 3) & 7;
  float acc = 0.f;
  #pragma unroll
  for (int jj = 0; jj < 16; ++jj) {
    const int k = ((jj + j0) & 15) << 2;
    const float4 xk = *reinterpret_cast<const float4*>(&xs[wave][k]);
    const float4 wk = *reinterpret_cast<const float4*>(&Wl[lane][k]);
    acc = fmaf(xk.x, wk.x, acc);
    acc = fmaf(xk.y, wk.y, acc);
    acc = fmaf(xk.z, wk.z, acc);
    acc = fmaf(xk.w, wk.w, acc);
  }
  he[row * DD + lane] = acc * s;
}

// ---------------------------------------------------------------------------
// CSR build: histogram -> 2-level exclusive scan -> cursor scatter
// ---------------------------------------------------------------------------
__global__ __launch_bounds__(256) void hgcn_hist(const int* __restrict__ ei,
                                                 int* __restrict__ cnt, int ne) {
  const int e = blockIdx.x * 256 + threadIdx.x;
  if (e < ne) atomicAdd(&cnt[ei[e]], 1);
}

__global__ __launch_bounds__(256) void hgcn_scan1(const int* __restrict__ cnt,
                                                  int* __restrict__ offs,
                                                  int* __restrict__ bsum, int n) {
  __shared__ int s[256];
  const int t = threadIdx.x;
  const int i = blockIdx.x * 256 + t;
  const int v = (i < n) ? cnt[i] : 0;
  s[t] = v;
  __syncthreads();
  for (int d = 1; d < 256; d <<= 1) {
    const int a = (t >= d) ? s[t - d] : 0;
    __syncthreads();
    s[t] += a;
    __syncthreads();
  }
  if (i < n) offs[i] = s[t] - v;          // exclusive within chunk
  if (t == 255) bsum[blockIdx.x] = s[255]; // chunk total
}

__global__ __launch_bounds__(256) void hgcn_scan2(int* __restrict__ bsum, int nb) {
  __shared__ int s[256];
  const int t = threadIdx.x;
  const int v = (t < nb) ? bsum[t] : 0;
  s[t] = v;
  __syncthreads();
  for (int d = 1; d < 256; d <<= 1) {
    const int a = (t >= d) ? s[t - d] : 0;
    __syncthreads();
    s[t] += a;
    __syncthreads();
  }
  if (t < nb) bsum[t] = s[t] - v;          // exclusive chunk bases
}

__global__ __launch_bounds__(256) void hgcn_scan3(int* __restrict__ offs,
                                                  const int* __restrict__ bsum,
                                                  int* __restrict__ cur, int n, int ne) {
  const int i = blockIdx.x * 256 + threadIdx.x;
  if (i < n) {
    const int o = offs[i] + bsum[i >> 8];
    offs[i] = o;
    cur[i] = o;
  }
  if (i == 0) offs[n] = ne;
}

__global__ __launch_bounds__(256) void hgcn_build(const int* __restrict__ ei,
                                                  const float* __restrict__ ew,
                                                  int* __restrict__ cur,
                                                  int* __restrict__ ccol,
                                                  float* __restrict__ cw, int ne) {
  const int e = blockIdx.x * 256 + threadIdx.x;
  if (e >= ne) return;
  const int row = ei[e];
  const int col = ei[ne + e];
  const int pos = atomicAdd(&cur[row], 1);
  ccol[pos] = col;
  cw[pos] = ew[e];
}

// ---------------------------------------------------------------------------
// Aggregate + fused epilogue: one wave per row.
// out[r] = proj(expmap0(relu(sum_e w_e * he[col_e])))
// ---------------------------------------------------------------------------
__global__ __launch_bounds__(256) void hgcn_aggregate(const float* __restrict__ he,
                                                      const int* __restrict__ offs,
                                                      const int* __restrict__ ccol,
                                                      const float* __restrict__ cw,
                                                      float* __restrict__ out, int n) {
  const int wave = threadIdx.x >> 6, lane = threadIdx.x & 63;
  const int row = blockIdx.x * 4 + wave;
  if (row >= n) return;
  const int beg = offs[row], end = offs[row + 1];
  float acc = 0.f;
  for (int base = beg; base < end; base += 64) {
    int m = end - base;
    if (m > 64) m = 64;
    int c = 0;
    float w = 0.f;
    if (lane < m) {
      c = ccol[base + lane];
      w = cw[base + lane];
    }
    for (int j = 0; j < m; ++j) {
      const int cj = __shfl(c, j);
      const float wj = __shfl(w, j);
      acc = fmaf(wj, he[(size_t)cj * DD + lane], acc);
    }
  }
  acc = fmaxf(acc, 0.f);
  float p = acc * acc;
  #pragma unroll
  for (int mm = 1; mm < 64; mm <<= 1) p += __shfl_xor(p, mm);
  const float nu = fmaxf(sqrtf(p), 1e-15f);
  const float th = tanhf(nu);
  float scale = th / nu;
  const float maxn = 1.0f - 4e-3f;
  if (th > maxn) scale = maxn / nu;
  out[(size_t)row * DD + lane] = acc * scale;
}

// ---------------------------------------------------------------------------
// Fallback path (round-1): atomic scatter, only if ws too small for CSR.
// ---------------------------------------------------------------------------
__global__ __launch_bounds__(256) void hgcn_scatter(const float* __restrict__ he,
                                                    const int* __restrict__ ei,
                                                    const float* __restrict__ ew,
                                                    float* __restrict__ sup, int ne) {
  const int t = blockIdx.x * 256 + threadIdx.x;
  const int e = t >> 4, l = t & 15;
  if (e >= ne) return;
  const int row = ei[e];
  const int col = ei[ne + e];
  const float w = ew[e];
  const float4 v = *reinterpret_cast<const float4*>(he + (size_t)col * DD + l * 4);
  float* dst = sup + (size_t)row * DD + l * 4;
  unsafeAtomicAdd(dst + 0, w * v.x);
  unsafeAtomicAdd(dst + 1, w * v.y);
  unsafeAtomicAdd(dst + 2, w * v.z);
  unsafeAtomicAdd(dst + 3, w * v.w);
}

__global__ __launch_bounds__(256) void hgcn_final(const float* __restrict__ sup,
                                                  float* __restrict__ out, int n) {
  const int t = blockIdx.x * 256 + threadIdx.x;
  const int r = t >> 4, l = t & 15;
  if (r >= n) return;
  float4 v = *reinterpret_cast<const float4*>(sup + (size_t)r * DD + l * 4);
  v.x = fmaxf(v.x, 0.f);
  v.y = fmaxf(v.y, 0.f);
  v.z = fmaxf(v.z, 0.f);
  v.w = fmaxf(v.w, 0.f);
  float p = v.x * v.x + v.y * v.y + v.z * v.z + v.w * v.w;
  p += __shfl_xor(p, 1);
  p += __shfl_xor(p, 2);
  p += __shfl_xor(p, 4);
  p += __shfl_xor(p, 8);
  const float nu = fmaxf(sqrtf(p), 1e-15f);
  const float th = tanhf(nu);
  float scale = th / nu;
  const float maxn = 1.0f - 4e-3f;
  if (th > maxn) scale = maxn / nu;
  float4 o;
  o.x = v.x * scale;
  o.y = v.y * scale;
  o.z = v.z * scale;
  o.w = v.w * scale;
  *reinterpret_cast<float4*>(out + (size_t)r * DD + l * 4) = o;
}

extern "C" void kernel_launch(void* const* d_in, const int* in_sizes, int n_in,
                              void* d_out, int out_size, void* d_ws, size_t ws_size,
                              hipStream_t stream) {
  const float* x  = (const float*)d_in[0];
  const float* W  = (const float*)d_in[1];
  const float* ew = (const float*)d_in[2];
  const int*   ei = (const int*)d_in[3];
  const int n  = in_sizes[0] / DD;   // 50000
  const int ne = in_sizes[2];        // 800000
  const int nb = (n + 255) / 256;    // scan chunks (196 <= 256)

  // ws layout (all 16B-aligned)
  size_t off_he   = 0;
  size_t off_ccol = off_he   + (size_t)n * DD * sizeof(float);
  size_t off_cw   = off_ccol + (size_t)ne * sizeof(int);
  size_t off_offs = off_cw   + (size_t)ne * sizeof(float);
  size_t off_cur  = off_offs + ((size_t)n + 4) * sizeof(int);
  size_t off_bsum = off_cur  + (size_t)n * sizeof(int);
  size_t need     = off_bsum + (size_t)nb * sizeof(int) + 64;

  if (ws_size >= need && nb <= 256) {
    // ---------------- CSR gather path ----------------
    float* he   = (float*)((char*)d_ws + off_he);
    int*   ccol = (int*)  ((char*)d_ws + off_ccol);
    float* cw   = (float*)((char*)d_ws + off_cw);
    int*   offs = (int*)  ((char*)d_ws + off_offs);
    int*   cur  = (int*)  ((char*)d_ws + off_cur);
    int*   bsum = (int*)  ((char*)d_ws + off_bsum);
    float* out  = (float*)d_out;

    hipMemsetAsync(cur, 0, (size_t)n * sizeof(int), stream);  // cur doubles as counts
    hipLaunchKernelGGL(hgcn_hist,   dim3((ne + 255) / 256), dim3(256), 0, stream, ei, cur, ne);
    hipLaunchKernelGGL(hgcn_scan1,  dim3(nb),               dim3(256), 0, stream, cur, offs, bsum, n);
    hipLaunchKernelGGL(hgcn_scan2,  dim3(1),                dim3(256), 0, stream, bsum, nb);
    hipLaunchKernelGGL(hgcn_scan3,  dim3(nb),               dim3(256), 0, stream, offs, bsum, cur, n, ne);
    hipLaunchKernelGGL(hgcn_linear, dim3((n + 3) / 4),      dim3(256), 0, stream, x, W, he, n);
    hipLaunchKernelGGL(hgcn_build,  dim3((ne + 255) / 256), dim3(256), 0, stream, ei, ew, cur, ccol, cw, ne);
    hipLaunchKernelGGL(hgcn_aggregate, dim3((n + 3) / 4),   dim3(256), 0, stream, he, offs, ccol, cw, out, n);
  } else {
    // ---------------- fallback: atomic scatter path ----------------
    float* he  = (float*)d_out;
    float* sup = (float*)d_ws;
    float* out = (float*)d_out;
    hipMemsetAsync(sup, 0, (size_t)n * DD * sizeof(float), stream);
    hipLaunchKernelGGL(hgcn_linear,  dim3((n + 3) / 4),           dim3(256), 0, stream, x, W, he, n);
    hipLaunchKernelGGL(hgcn_scatter, dim3((ne * 16 + 255) / 256), dim3(256), 0, stream, he, ei, ew, sup, ne);
    hipLaunchKernelGGL(hgcn_final,   dim3((n * 16 + 255) / 256),  dim3(256), 0, stream, sup, out, n);
  }
}

// Round 3
// 140.269 us; speedup vs baseline: 5.2244x; 1.3399x over previous
//
#include <hip/hip_runtime.h>
#include <hip/hip_bf16.h>
#include <math.h>

#define DD 64
typedef unsigned long long u64;
typedef unsigned int u32;
typedef unsigned short u16;

// ---------------------------------------------------------------------------
// Linear: he = bf16( (x @ W^T) * artanh(||x||)/||x|| )   (exact telescoped
// logmap0(mobius_matvec(W,x,c=1))). One wave per row.
// ---------------------------------------------------------------------------
__global__ __launch_bounds__(256) void hgcn_linear(const float* __restrict__ x,
                                                   const float* __restrict__ W,
                                                   __hip_bfloat16* __restrict__ he,
                                                   int n) {
  __shared__ float Wl[64][68];
  __shared__ float xs[4][64];
  const int tid = threadIdx.x;
  for (int i = tid; i < 64 * 64; i += 256) Wl[i >> 6][i & 63] = W[i];
  const int wave = tid >> 6, lane = tid & 63;
  const int row = blockIdx.x * 4 + wave;
  float xv = 0.f;
  if (row < n) xv = x[row * DD + lane];
  xs[wave][lane] = xv;
  __syncthreads();
  if (row >= n) return;

  float nx2 = xv * xv;
  #pragma unroll
  for (int m = 1; m < 64; m <<= 1) nx2 += __shfl_xor(nx2, m);
  const float nx = fmaxf(sqrtf(nx2), 1e-15f);
  const float z  = fminf(nx, 1.f - 1e-7f);
  const float s  = atanhf(z) / nx;

  const int j0 = (lane >> 3) & 7;
  float acc = 0.f;
  #pragma unroll
  for (int jj = 0; jj < 16; ++jj) {
    const int k = ((jj + j0) & 15) << 2;
    const float4 xk = *reinterpret_cast<const float4*>(&xs[wave][k]);
    const float4 wk = *reinterpret_cast<const float4*>(&Wl[lane][k]);
    acc = fmaf(xk.x, wk.x, acc);
    acc = fmaf(xk.y, wk.y, acc);
    acc = fmaf(xk.z, wk.z, acc);
    acc = fmaf(xk.w, wk.w, acc);
  }
  he[row * DD + lane] = __float2bfloat16(acc * s);
}

// ---------------------------------------------------------------------------
// Row histogram (into offs array used as counts; memset to 0 first)
// ---------------------------------------------------------------------------
__global__ __launch_bounds__(256) void hgcn_hist(const int* __restrict__ ei,
                                                 int* __restrict__ cnt, int ne) {
  const int e = blockIdx.x * 256 + threadIdx.x;
  if (e < ne) atomicAdd(&cnt[ei[e]], 1);
}

// in-place exclusive scan over 256-chunks (offs doubles as counts)
__global__ __launch_bounds__(256) void hgcn_scan1(int* __restrict__ offs,
                                                  int* __restrict__ bsum, int n) {
  __shared__ int s[256];
  const int t = threadIdx.x;
  const int i = blockIdx.x * 256 + t;
  const int v = (i < n) ? offs[i] : 0;
  s[t] = v;
  __syncthreads();
  for (int d = 1; d < 256; d <<= 1) {
    const int a = (t >= d) ? s[t - d] : 0;
    __syncthreads();
    s[t] += a;
    __syncthreads();
  }
  if (i < n) offs[i] = s[t] - v;
  if (t == 255) bsum[blockIdx.x] = s[255];
}

__global__ __launch_bounds__(256) void hgcn_scan2(int* __restrict__ bsum, int nb) {
  __shared__ int s[256];
  const int t = threadIdx.x;
  const int v = (t < nb) ? bsum[t] : 0;
  s[t] = v;
  __syncthreads();
  for (int d = 1; d < 256; d <<= 1) {
    const int a = (t >= d) ? s[t - d] : 0;
    __syncthreads();
    s[t] += a;
    __syncthreads();
  }
  if (t < nb) bsum[t] = s[t] - v;
}

// finalize offs; init bucket cursors to bucket bases (= offs[b*256])
__global__ __launch_bounds__(256) void hgcn_scan3(int* __restrict__ offs,
                                                  const int* __restrict__ bsum,
                                                  int* __restrict__ bcur, int n, int ne) {
  const int i = blockIdx.x * 256 + threadIdx.x;
  if (i < n) {
    const int o = offs[i] + bsum[i >> 8];
    offs[i] = o;
    if ((i & 255) == 0) bcur[i >> 8] = o;
  }
  if (i == 0) offs[n] = ne;
}

// ---------------------------------------------------------------------------
// Bin pass 1: scatter packed edges (w:32|row:16|col:16) into 256-row bucket
// regions. Per-block LDS hist -> one contiguous run reservation per bucket
// -> near-coalesced run writes (fixes the 13x write amplification).
// ---------------------------------------------------------------------------
#define BINB 1024
#define BINC 6144
__global__ __launch_bounds__(1024) void hgcn_bin(const int* __restrict__ ei,
                                                 const float* __restrict__ ew,
                                                 int* __restrict__ bcur,
                                                 u64* __restrict__ stage,
                                                 int ne, int nbuck) {
  __shared__ int h[256], cur[256], gp[256];
  const int tid = threadIdx.x;
  const int eb = blockIdx.x * BINC;
  const int m = min(BINC, ne - eb);
  if (tid < 256) { h[tid] = 0; cur[tid] = 0; }
  __syncthreads();
  for (int i = tid; i < m; i += BINB) atomicAdd(&h[ei[eb + i] >> 8], 1);
  __syncthreads();
  if (tid < 256) gp[tid] = (tid < nbuck && h[tid] > 0) ? atomicAdd(&bcur[tid], h[tid]) : 0;
  __syncthreads();
  for (int i = tid; i < m; i += BINB) {
    const int r = ei[eb + i];
    const int c = ei[ne + eb + i];
    const float w = ew[eb + i];
    const int b = r >> 8;
    const int pos = gp[b] + atomicAdd(&cur[b], 1);
    stage[pos] = ((u64)__float_as_uint(w) << 32) | ((u32)(r & 0xffff) << 16) | (u32)(c & 0xffff);
  }
}

// ---------------------------------------------------------------------------
// Bin pass 2: one block per bucket; LDS hist+scan over 256 local rows, then
// permute bucket entries into exact CSR row order (contiguous region).
// ---------------------------------------------------------------------------
__global__ __launch_bounds__(256) void hgcn_regroup(const u64* __restrict__ stage,
                                                    const int* __restrict__ offs,
                                                    u64* __restrict__ csr, int n) {
  const int b = blockIdx.x;
  const int rlo = b << 8;
  const int rhi = min(rlo + 256, n);
  const int sbase = offs[rlo];
  const int m = offs[rhi] - sbase;
  __shared__ int lh[256], ls[256], lc[256];
  const int t = threadIdx.x;
  lh[t] = 0; lc[t] = 0;
  __syncthreads();
  for (int i = t; i < m; i += 256)
    atomicAdd(&lh[(int)((stage[sbase + i] >> 16) & 0xff)], 1);
  __syncthreads();
  const int v = lh[t];
  ls[t] = v;
  __syncthreads();
  for (int d = 1; d < 256; d <<= 1) {
    const int a = (t >= d) ? ls[t - d] : 0;
    __syncthreads();
    ls[t] += a;
    __syncthreads();
  }
  lh[t] = ls[t] - v;      // exclusive scan, indexed by local row
  __syncthreads();
  for (int i = t; i < m; i += 256) {
    const u64 p = stage[sbase + i];
    const int rl = (int)((p >> 16) & 0xff);
    const int pos = lh[rl] + atomicAdd(&lc[rl], 1);
    csr[sbase + pos] = p;
  }
}

// ---------------------------------------------------------------------------
// Aggregate + fused epilogue. One wave per row, 8 groups x 8 lanes:
// 8 edges gathered in flight per wave (bf16 he rows, 128B each).
// ---------------------------------------------------------------------------
__global__ __launch_bounds__(256) void hgcn_agg(const u16* __restrict__ he,
                                                const int* __restrict__ offs,
                                                const u64* __restrict__ pe,
                                                float* __restrict__ out, int n) {
  const int wave = threadIdx.x >> 6, lane = threadIdx.x & 63;
  const int g = lane >> 3, l = lane & 7;
  const int row = blockIdx.x * 4 + wave;
  if (row >= n) return;
  const int beg = offs[row], end = offs[row + 1];
  float a0=0.f,a1=0.f,a2=0.f,a3=0.f,a4=0.f,a5=0.f,a6=0.f,a7=0.f;
  for (int base = beg; base < end; base += 64) {
    const int m = min(64, end - base);
    int c = 0; float w = 0.f;
    if (lane < m) {
      const u64 p = pe[base + lane];
      c = (int)(p & 0xffffu);
      w = __uint_as_float((u32)(p >> 32));
    }
    const int nj = (m + 7) >> 3;
    for (int j = 0; j < nj; ++j) {
      const int src = j * 8 + g;
      const int cj = __shfl(c, src);
      const float wj = __shfl(w, src);
      const uint4 q = reinterpret_cast<const uint4*>(he + ((size_t)cj << 6))[l];
      a0 = fmaf(wj, __uint_as_float(q.x << 16), a0);
      a1 = fmaf(wj, __uint_as_float(q.x & 0xffff0000u), a1);
      a2 = fmaf(wj, __uint_as_float(q.y << 16), a2);
      a3 = fmaf(wj, __uint_as_float(q.y & 0xffff0000u), a3);
      a4 = fmaf(wj, __uint_as_float(q.z << 16), a4);
      a5 = fmaf(wj, __uint_as_float(q.z & 0xffff0000u), a5);
      a6 = fmaf(wj, __uint_as_float(q.w << 16), a6);
      a7 = fmaf(wj, __uint_as_float(q.w & 0xffff0000u), a7);
    }
  }
  #pragma unroll
  for (int msk = 8; msk <= 32; msk <<= 1) {
    a0 += __shfl_xor(a0, msk); a1 += __shfl_xor(a1, msk);
    a2 += __shfl_xor(a2, msk); a3 += __shfl_xor(a3, msk);
    a4 += __shfl_xor(a4, msk); a5 += __shfl_xor(a5, msk);
    a6 += __shfl_xor(a6, msk); a7 += __shfl_xor(a7, msk);
  }
  a0=fmaxf(a0,0.f); a1=fmaxf(a1,0.f); a2=fmaxf(a2,0.f); a3=fmaxf(a3,0.f);
  a4=fmaxf(a4,0.f); a5=fmaxf(a5,0.f); a6=fmaxf(a6,0.f); a7=fmaxf(a7,0.f);
  float p = a0*a0+a1*a1+a2*a2+a3*a3+a4*a4+a5*a5+a6*a6+a7*a7;
  p += __shfl_xor(p, 1); p += __shfl_xor(p, 2); p += __shfl_xor(p, 4);
  const float nu = fmaxf(sqrtf(p), 1e-15f);
  const float th = tanhf(nu);
  float scale = th / nu;
  const float maxn = 1.0f - 4e-3f;
  if (th > maxn) scale = maxn / nu;
  if (g == 0) {
    float4 o1 = {a0*scale, a1*scale, a2*scale, a3*scale};
    float4 o2 = {a4*scale, a5*scale, a6*scale, a7*scale};
    float4* op = reinterpret_cast<float4*>(out + (size_t)row * DD + (size_t)l * 8);
    op[0] = o1; op[1] = o2;
  }
}

// ---------------------------------------------------------------------------
// Deep fallback (tiny ws): round-1 atomic scatter path, fp32.
// ---------------------------------------------------------------------------
__global__ __launch_bounds__(256) void hgcn_linf32(const float* __restrict__ x,
                                                   const float* __restrict__ W,
                                                   float* __restrict__ he, int n) {
  __shared__ float Wl[64][68];
  __shared__ float xs[4][64];
  const int tid = threadIdx.x;
  for (int i = tid; i < 64 * 64; i += 256) Wl[i >> 6][i & 63] = W[i];
  const int wave = tid >> 6, lane = tid & 63;
  const int row = blockIdx.x * 4 + wave;
  float xv = 0.f;
  if (row < n) xv = x[row * DD + lane];
  xs[wave][lane] = xv;
  __syncthreads();
  if (row >= n) return;
  float nx2 = xv * xv;
  #pragma unroll
  for (int m = 1; m < 64; m <<= 1) nx2 += __shfl_xor(nx2, m);
  const float nx = fmaxf(sqrtf(nx2), 1e-15f);
  const float s = atanhf(fminf(nx, 1.f - 1e-7f)) / nx;
  const int j0 = (lane >> 3) & 7;
  float acc = 0.f;
  #pragma unroll
  for (int jj = 0; jj < 16; ++jj) {
    const int k = ((jj + j0) & 15) << 2;
    const float4 xk = *reinterpret_cast<const float4*>(&xs[wave][k]);
    const float4 wk = *reinterpret_cast<const float4*>(&Wl[lane][k]);
    acc = fmaf(xk.x, wk.x, acc); acc = fmaf(xk.y, wk.y, acc);
    acc = fmaf(xk.z, wk.z, acc); acc = fmaf(xk.w, wk.w, acc);
  }
  he[row * DD + lane] = acc * s;
}

__global__ __launch_bounds__(256) void hgcn_scatter(const float* __restrict__ he,
                                                    const int* __restrict__ ei,
                                                    const float* __restrict__ ew,
                                                    float* __restrict__ sup, int ne) {
  const int t = blockIdx.x * 256 + threadIdx.x;
  const int e = t >> 4, l = t & 15;
  if (e >= ne) return;
  const int row = ei[e];
  const int col = ei[ne + e];
  const float w = ew[e];
  const float4 v = *reinterpret_cast<const float4*>(he + (size_t)col * DD + l * 4);
  float* dst = sup + (size_t)row * DD + l * 4;
  unsafeAtomicAdd(dst + 0, w * v.x);
  unsafeAtomicAdd(dst + 1, w * v.y);
  unsafeAtomicAdd(dst + 2, w * v.z);
  unsafeAtomicAdd(dst + 3, w * v.w);
}

__global__ __launch_bounds__(256) void hgcn_final(const float* __restrict__ sup,
                                                  float* __restrict__ out, int n) {
  const int t = blockIdx.x * 256 + threadIdx.x;
  const int r = t >> 4, l = t & 15;
  if (r >= n) return;
  float4 v = *reinterpret_cast<const float4*>(sup + (size_t)r * DD + l * 4);
  v.x = fmaxf(v.x, 0.f); v.y = fmaxf(v.y, 0.f);
  v.z = fmaxf(v.z, 0.f); v.w = fmaxf(v.w, 0.f);
  float p = v.x*v.x + v.y*v.y + v.z*v.z + v.w*v.w;
  p += __shfl_xor(p, 1); p += __shfl_xor(p, 2);
  p += __shfl_xor(p, 4); p += __shfl_xor(p, 8);
  const float nu = fmaxf(sqrtf(p), 1e-15f);
  const float th = tanhf(nu);
  float scale = th / nu;
  const float maxn = 1.0f - 4e-3f;
  if (th > maxn) scale = maxn / nu;
  float4 o = {v.x*scale, v.y*scale, v.z*scale, v.w*scale};
  *reinterpret_cast<float4*>(out + (size_t)r * DD + l * 4) = o;
}

extern "C" void kernel_launch(void* const* d_in, const int* in_sizes, int n_in,
                              void* d_out, int out_size, void* d_ws, size_t ws_size,
                              hipStream_t stream) {
  const float* x  = (const float*)d_in[0];
  const float* W  = (const float*)d_in[1];
  const float* ew = (const float*)d_in[2];
  const int*   ei = (const int*)d_in[3];
  const int n  = in_sizes[0] / DD;   // 50000
  const int ne = in_sizes[2];        // 800000
  const int nb = (n + 255) / 256;    // scan chunks == bucket count (196)

  // ws layout
  size_t off_he    = 0;
  size_t off_stage = off_he + (((size_t)n * DD * 2 + 15) / 16) * 16;
  size_t off_csr   = off_stage + (size_t)ne * 8;
  size_t off_offs  = off_csr + (size_t)ne * 8;
  size_t off_bsum  = off_offs + ((((size_t)n + 1) * 4 + 15) / 16) * 16;
  size_t off_bcur  = off_bsum + 1024;
  size_t need      = off_bcur + 1024 + 64;

  if (ws_size >= need && n <= 65536 && nb <= 256) {
    __hip_bfloat16* he = (__hip_bfloat16*)((char*)d_ws + off_he);
    u64*  stage = (u64*)((char*)d_ws + off_stage);
    u64*  csr   = (u64*)((char*)d_ws + off_csr);
    int*  offs  = (int*)((char*)d_ws + off_offs);
    int*  bsum  = (int*)((char*)d_ws + off_bsum);
    int*  bcur  = (int*)((char*)d_ws + off_bcur);
    float* out  = (float*)d_out;

    hipMemsetAsync(offs, 0, ((size_t)n + 1) * sizeof(int), stream);
    hipLaunchKernelGGL(hgcn_hist,    dim3((ne + 255) / 256),        dim3(256),  0, stream, ei, offs, ne);
    hipLaunchKernelGGL(hgcn_scan1,   dim3(nb),                      dim3(256),  0, stream, offs, bsum, n);
    hipLaunchKernelGGL(hgcn_scan2,   dim3(1),                       dim3(256),  0, stream, bsum, nb);
    hipLaunchKernelGGL(hgcn_scan3,   dim3(nb),                      dim3(256),  0, stream, offs, bsum, bcur, n, ne);
    hipLaunchKernelGGL(hgcn_linear,  dim3((n + 3) / 4),             dim3(256),  0, stream, x, W, he, n);
    hipLaunchKernelGGL(hgcn_bin,     dim3((ne + BINC - 1) / BINC),  dim3(BINB), 0, stream, ei, ew, bcur, stage, ne, nb);
    hipLaunchKernelGGL(hgcn_regroup, dim3(nb),                      dim3(256),  0, stream, stage, offs, csr, n);
    hipLaunchKernelGGL(hgcn_agg,     dim3((n + 3) / 4),             dim3(256),  0, stream, (const u16*)he, offs, csr, out, n);
  } else {
    float* he  = (float*)d_out;
    float* sup = (float*)d_ws;
    float* out = (float*)d_out;
    hipMemsetAsync(sup, 0, (size_t)n * DD * sizeof(float), stream);
    hipLaunchKernelGGL(hgcn_linf32,  dim3((n + 3) / 4),            dim3(256), 0, stream, x, W, he, n);
    hipLaunchKernelGGL(hgcn_scatter, dim3((ne * 16 + 255) / 256),  dim3(256), 0, stream, he, ei, ew, sup, ne);
    hipLaunchKernelGGL(hgcn_final,   dim3((n * 16 + 255) / 256),   dim3(256), 0, stream, sup, out, n);
  }
}